// Round 4
// baseline (261.096 us; speedup 1.0000x reference)
//
#include <hip/hip_runtime.h>
#include <math.h>

#define DIM 96
#define NE 6
#define NB 8
#define H 192
#define W 192
#define HW (H * W)
#define NQ 4            // pool partial quarters
#define QF4 (HW / 4 / NQ)  // 2304 float4 per quarter

typedef float f2 __attribute__((ext_vector_type(2)));

// ---------------- Kernel A: partial max+sum per (b,c,quarter) ----------------
__global__ __launch_bounds__(256) void pool_partial(const float* __restrict__ x,
                                                    float* __restrict__ pmax,
                                                    float* __restrict__ psum) {
    int bc = blockIdx.x;       // 0..767
    int q = blockIdx.y;        // 0..3
    const float4* xp = (const float4*)(x + (size_t)bc * HW) + q * QF4;
    int tid = threadIdx.x;
    float vmax = -INFINITY, vsum = 0.f;
    for (int i = tid; i < QF4; i += 256) {
        float4 v = xp[i];
        vmax = fmaxf(vmax, fmaxf(fmaxf(v.x, v.y), fmaxf(v.z, v.w)));
        vsum += v.x + v.y + v.z + v.w;
    }
    for (int off = 32; off; off >>= 1) {
        vmax = fmaxf(vmax, __shfl_down(vmax, off, 64));
        vsum += __shfl_down(vsum, off, 64);
    }
    __shared__ float smax[4], ssum[4];
    if ((tid & 63) == 0) { smax[tid >> 6] = vmax; ssum[tid >> 6] = vsum; }
    __syncthreads();
    if (tid == 0) {
        float m = smax[0], s = ssum[0];
        for (int w = 1; w < 4; ++w) { m = fmaxf(m, smax[w]); s += ssum[w]; }
        pmax[q * (NB * DIM) + bc] = m;
        psum[q * (NB * DIM) + bc] = s;
    }
}

// ---------------- Kernel B: gate (parallel dots from LDS) ----------------
__global__ __launch_bounds__(128) void gate_kernel(const float* __restrict__ pmax,
                                                   const float* __restrict__ psum,
                                                   const float* __restrict__ w_fc0,
                                                   const float* __restrict__ b_fc0,
                                                   const float* __restrict__ w_fc1,
                                                   const float* __restrict__ b_fc1,
                                                   float* __restrict__ cof) {
    __shared__ float sp[NB * DIM];       // pooled
    __shared__ float sw1[NE * DIM], sw0[NE * DIM];
    __shared__ float z1s[NB * NE], z0s[NB * NE];
    int tid = threadIdx.x;
    // merge pool partials -> pooled = max + mean
    for (int i = tid; i < NB * DIM; i += 128) {
        float m = pmax[i], s = psum[i];
        for (int q = 1; q < NQ; ++q) {
            m = fmaxf(m, pmax[q * (NB * DIM) + i]);
            s += psum[q * (NB * DIM) + i];
        }
        sp[i] = m + s * (1.0f / (float)HW);
    }
    for (int i = tid; i < NE * DIM; i += 128) {
        sw1[i] = w_fc1[i];
        sw0[i] = w_fc0[i];
    }
    __syncthreads();
    if (tid < 2 * NB * NE) {             // 96 threads: one dot each
        int pair = (tid < NB * NE) ? tid : tid - NB * NE;
        int b = pair / NE, e = pair - b * NE;
        const float* wp = ((tid < NB * NE) ? sw1 : sw0) + e * DIM;
        float z = (tid < NB * NE) ? b_fc1[e] : b_fc0[e];
        const float* pp = sp + b * DIM;
        for (int i = 0; i < DIM; ++i) z = fmaf(pp[i], wp[i], z);
        if (tid < NB * NE) z1s[pair] = z; else z0s[pair] = z;
    }
    __syncthreads();
    if (tid < NB) {
        int b = tid;
        float g[NE], noise[NE];
        for (int e = 0; e < NE; ++e) {
            float z1 = z1s[b * NE + e], z0 = z0s[b * NE + e];
            g[e] = (z1 > 0.f) ? z1 : 0.2f * z1;                 // leaky_relu 0.2
            noise[e] = (z0 > 20.f) ? z0 : log1pf(expf(z0));     // softplus
        }
        float mu = 0.f;
        for (int e = 0; e < NE; ++e) mu += noise[e];
        mu *= (1.0f / NE);
        float var = 0.f;
        for (int e = 0; e < NE; ++e) { float d = noise[e] - mu; var += d * d; }
        var *= (1.0f / (NE - 1));                               // ddof=1
        float sd = sqrtf(var);
        float scores[NE];
        for (int e = 0; e < NE; ++e) scores[e] = g[e] + (noise[e] - mu) / sd;
        bool chosen[NE] = {false, false, false, false, false, false};
        for (int k = 0; k < 3; ++k) {                           // top-3, ties -> lowest idx
            float best = -INFINITY; int bi = 0;
            for (int e = 0; e < NE; ++e)
                if (!chosen[e] && scores[e] > best) { best = scores[e]; bi = e; }
            chosen[bi] = true;
        }
        float m = -INFINITY;
        for (int e = 0; e < NE; ++e) if (chosen[e]) m = fmaxf(m, g[e]);
        float s = 0.f;
        for (int e = 0; e < NE; ++e) if (chosen[e]) s += expf(g[e] - m);
        float inv = 1.0f / s;
        for (int e = 0; e < NE; ++e)
            cof[b * NE + e] = chosen[e] ? expf(g[e] - m) * inv : 0.f;
    }
}

// ---------------- Kernel C: fused top-k expert dwconv-relu-dwconv (v4) ----------------
// No LDS, no barrier: x is L2/L3-resident (27 KB/wave working set), so each lane
// reads its 5-col window directly from global with a 4-slot rotating register
// window (one full row of prefetch distance). Conv math identical to v3
// (pair-packed e0,e1 + scalar e2) -> bit-identical output.
#define TY 32
#define RPW 8                 // rows per wave

__device__ __forceinline__ f2 splat2(float v) { f2 r; r.x = v; r.y = v; return r; }

// scalar 3x3 chain (association: w2*A2+bb innermost, rows A,B,C outward)
__device__ __forceinline__ float c3(const float* Wt, float bb,
                                    const float* A, const float* B,
                                    const float* Cc, int o) {
    float s = fmaf(Wt[2], A[o + 2], bb);
    s = fmaf(Wt[1], A[o + 1], s);
    s = fmaf(Wt[0], A[o], s);
    s = fmaf(Wt[5], B[o + 2], s);
    s = fmaf(Wt[4], B[o + 1], s);
    s = fmaf(Wt[3], B[o], s);
    s = fmaf(Wt[8], Cc[o + 2], s);
    s = fmaf(Wt[7], Cc[o + 1], s);
    s = fmaf(Wt[6], Cc[o], s);
    return s;
}

// packed pair-of-experts chain, x operands are splatted scalars (conv1)
__device__ __forceinline__ f2 c3p(const f2* Wt, f2 bb,
                                  const float* A, const float* B,
                                  const float* Cc, int o) {
    f2 s = __builtin_elementwise_fma(Wt[2], splat2(A[o + 2]), bb);
    s = __builtin_elementwise_fma(Wt[1], splat2(A[o + 1]), s);
    s = __builtin_elementwise_fma(Wt[0], splat2(A[o]), s);
    s = __builtin_elementwise_fma(Wt[5], splat2(B[o + 2]), s);
    s = __builtin_elementwise_fma(Wt[4], splat2(B[o + 1]), s);
    s = __builtin_elementwise_fma(Wt[3], splat2(B[o]), s);
    s = __builtin_elementwise_fma(Wt[8], splat2(Cc[o + 2]), s);
    s = __builtin_elementwise_fma(Wt[7], splat2(Cc[o + 1]), s);
    s = __builtin_elementwise_fma(Wt[6], splat2(Cc[o]), s);
    return s;
}

// packed chain with pair operands (conv2: ys halves are per-expert already)
__device__ __forceinline__ f2 c3q(const f2* Wt, f2 bb,
                                  const f2* A, const f2* B,
                                  const f2* Cc, int o) {
    f2 s = __builtin_elementwise_fma(Wt[2], A[o + 2], bb);
    s = __builtin_elementwise_fma(Wt[1], A[o + 1], s);
    s = __builtin_elementwise_fma(Wt[0], A[o], s);
    s = __builtin_elementwise_fma(Wt[5], B[o + 2], s);
    s = __builtin_elementwise_fma(Wt[4], B[o + 1], s);
    s = __builtin_elementwise_fma(Wt[3], B[o], s);
    s = __builtin_elementwise_fma(Wt[8], Cc[o + 2], s);
    s = __builtin_elementwise_fma(Wt[7], Cc[o + 1], s);
    s = __builtin_elementwise_fma(Wt[6], Cc[o], s);
    return s;
}

// load one x row's 5-col window (cols 3*lane-1 .. 3*lane+3) from global;
// OOB rows (wave-uniform) and OOB cols (lane 0 / lane 63) read as 0.
#define LOADROW(xr, dst) do {                                         \
    int _r = (xr);                                                    \
    if (_r >= 0 && _r < H) {                                          \
        const float* _q = xl + (size_t)_r * W;                        \
        float _v0 = _q[offm1];                                        \
        float _v1 = _q[0];                                            \
        float _v2 = _q[1];                                            \
        float _v3 = _q[2];                                            \
        float _v4 = _q[off3];                                         \
        if (l0)  _v0 = 0.f;                                           \
        if (l63) _v4 = 0.f;                                           \
        (dst)[0] = _v0; (dst)[1] = _v1; (dst)[2] = _v2;               \
        (dst)[3] = _v3; (dst)[4] = _v4;                               \
    } else {                                                          \
        (dst)[0] = 0.f; (dst)[1] = 0.f; (dst)[2] = 0.f;               \
        (dst)[3] = 0.f; (dst)[4] = 0.f;                               \
    }                                                                 \
} while (0)

__global__ __launch_bounds__(256, 3) void moe_kernel(const float* __restrict__ x,
                                                     const float* __restrict__ ew1,
                                                     const float* __restrict__ eb1,
                                                     const float* __restrict__ ew2,
                                                     const float* __restrict__ eb2,
                                                     const float* __restrict__ cof,
                                                     float* __restrict__ out) {
    const int sb = blockIdx.x;           // stripe 0..5
    const int c = blockIdx.y;
    const int b = blockIdx.z;
    const int ty0 = sb * TY;
    const int tid = threadIdx.x;
    const int lane = tid & 63;
    const int wv = tid >> 6;
    const bool l0 = (lane == 0);
    const bool l63 = (lane == 63);

    // ---- compact the (always exactly 3) chosen experts; hoist to SGPR ----
    const float* cofb = cof + b * NE;
    int e0 = 0, e1 = 0, e2 = 0;
    float q0 = 0.f, q1 = 0.f, q2 = 0.f;
    int n = 0;
    #pragma unroll
    for (int e = 0; e < NE; ++e) {
        float ce = cofb[e];
        if (ce != 0.f) {
            if (n == 0)      { e0 = e; q0 = ce; }
            else if (n == 1) { e1 = e; q1 = ce; }
            else if (n == 2) { e2 = e; q2 = ce; }
            ++n;
        }
    }
    e0 = __builtin_amdgcn_readfirstlane(e0);
    e1 = __builtin_amdgcn_readfirstlane(e1);
    e2 = __builtin_amdgcn_readfirstlane(e2);
    q0 = __int_as_float(__builtin_amdgcn_readfirstlane(__float_as_int(q0)));
    q1 = __int_as_float(__builtin_amdgcn_readfirstlane(__float_as_int(q1)));
    q2 = __int_as_float(__builtin_amdgcn_readfirstlane(__float_as_int(q2)));

    // weights: pair (e0,e1) packed, e2 scalar
    f2 W1p[9], W2p[9];
    float W1s[9], W2s[9];
    {
        const float* p10 = ew1 + (size_t)(e0 * DIM + c) * 9;
        const float* p11 = ew1 + (size_t)(e1 * DIM + c) * 9;
        const float* p12 = ew1 + (size_t)(e2 * DIM + c) * 9;
        const float* p20 = ew2 + (size_t)(e0 * DIM + c) * 9;
        const float* p21 = ew2 + (size_t)(e1 * DIM + c) * 9;
        const float* p22 = ew2 + (size_t)(e2 * DIM + c) * 9;
        #pragma unroll
        for (int k = 0; k < 9; ++k) {
            W1p[k].x = p10[k]; W1p[k].y = p11[k]; W1s[k] = p12[k];
            W2p[k].x = p20[k]; W2p[k].y = p21[k]; W2s[k] = p22[k];
        }
    }
    f2 B1p, B2p;
    B1p.x = eb1[e0 * DIM + c]; B1p.y = eb1[e1 * DIM + c];
    B2p.x = eb2[e0 * DIM + c]; B2p.y = eb2[e1 * DIM + c];
    const float B1s = eb1[e2 * DIM + c];
    const float B2s = eb2[e2 * DIM + c];
    const float CE0 = q0, CE1 = q1, CE2 = q2;

    const int r0 = ty0 + wv * RPW;       // first conv2 output row of this wave
    const float* xl = x + ((size_t)(b * DIM + c)) * HW + 3 * lane;  // col 3*lane
    const int offm1 = l0 ? 0 : -1;       // clamped col offsets (value zeroed after load)
    const int off3  = l63 ? 2 : 3;

    float X[4][5];                       // rotating x window: 4 rows x 5 cols
    f2 Yp[3][5];                         // pair-expert ys window: 3 rows x 5 cols
    float Ysc[3][5];                     // scalar-expert ys window
    LOADROW(r0 - 2, X[0]);
    LOADROW(r0 - 1, X[1]);
    LOADROW(r0,     X[2]);

    float* op = out + ((size_t)(b * DIM + c)) * HW + (size_t)r0 * W + 3 * lane;
    const f2 zero2 = splat2(0.f);

    #pragma unroll
    for (int j = 0; j < RPW + 2; ++j) {  // ys row ry = r0-1+j; out row r0+j-2 for j>=2
        if (j <= RPW)                    // prefetch row r0+j+1 (used as xC next iter)
            LOADROW(r0 + j + 1, X[(j + 3) & 3]);
        const float* xA = X[j & 3];          // row ry-1
        const float* xB = X[(j + 1) & 3];    // row ry
        const float* xC = X[(j + 2) & 3];    // row ry+1

        // conv1 + bias + relu
        f2 y0p = c3p(W1p, B1p, xA, xB, xC, 0);
        f2 y1p = c3p(W1p, B1p, xA, xB, xC, 1);
        f2 y2p = c3p(W1p, B1p, xA, xB, xC, 2);
        float y0s = c3(W1s, B1s, xA, xB, xC, 0);
        float y1s = c3(W1s, B1s, xA, xB, xC, 1);
        float y2s = c3(W1s, B1s, xA, xB, xC, 2);
        y0p = __builtin_elementwise_max(y0p, zero2);
        y1p = __builtin_elementwise_max(y1p, zero2);
        y2p = __builtin_elementwise_max(y2p, zero2);
        y0s = fmaxf(y0s, 0.f); y1s = fmaxf(y1s, 0.f); y2s = fmaxf(y2s, 0.f);
        if (j == 0 || j == RPW + 1) {        // only edge rows can be out of image
            int ry = r0 - 1 + j;
            if (ry < 0 || ry >= H) {
                y0p = zero2; y1p = zero2; y2p = zero2;
                y0s = 0.f; y1s = 0.f; y2s = 0.f;  // conv2 zero-pad
            }
        }
        // halo columns via shuffles (per expert half)
        float ylpx = __shfl_up(y2p.x, 1), ylpy = __shfl_up(y2p.y, 1);
        float yls = __shfl_up(y2s, 1);
        float yrpx = __shfl_down(y0p.x, 1), yrpy = __shfl_down(y0p.y, 1);
        float yrs = __shfl_down(y0s, 1);
        if (l0)  { ylpx = 0.f; ylpy = 0.f; yls = 0.f; }   // ys col -1 == 0
        if (l63) { yrpx = 0.f; yrpy = 0.f; yrs = 0.f; }   // ys col 192 == 0
        f2* ywp = Yp[j % 3];
        float* yws = Ysc[j % 3];
        ywp[0].x = ylpx; ywp[0].y = ylpy;
        ywp[1] = y0p; ywp[2] = y1p; ywp[3] = y2p;
        ywp[4].x = yrpx; ywp[4].y = yrpy;
        yws[0] = yls; yws[1] = y0s; yws[2] = y1s; yws[3] = y2s; yws[4] = yrs;

        if (j >= 2) {
            const f2* pA = Yp[(j + 1) % 3];      // ys row ro-1
            const f2* pB = Yp[(j + 2) % 3];      // ys row ro
            const f2* pC = ywp;                  // ys row ro+1
            const float* sA = Ysc[(j + 1) % 3];
            const float* sB = Ysc[(j + 2) % 3];
            const float* sC = yws;
            f2 s0p = c3q(W2p, B2p, pA, pB, pC, 0);
            f2 s1p = c3q(W2p, B2p, pA, pB, pC, 1);
            f2 s2p = c3q(W2p, B2p, pA, pB, pC, 2);
            float s0s = c3(W2s, B2s, sA, sB, sC, 0);
            float s1s = c3(W2s, B2s, sA, sB, sC, 1);
            float s2s = c3(W2s, B2s, sA, sB, sC, 2);
            // accumulate in the SAME order as v2: e0, e1, e2 fma chain
            float a0 = fmaf(CE2, s0s, fmaf(CE1, s0p.y, fmaf(CE0, s0p.x, 0.f)));
            float a1 = fmaf(CE2, s1s, fmaf(CE1, s1p.y, fmaf(CE0, s1p.x, 0.f)));
            float a2 = fmaf(CE2, s2s, fmaf(CE1, s2p.y, fmaf(CE0, s2p.x, 0.f)));
            op[0] = a0; op[1] = a1; op[2] = a2;
            op += W;
        }
    }
}

extern "C" void kernel_launch(void* const* d_in, const int* in_sizes, int n_in,
                              void* d_out, int out_size, void* d_ws, size_t ws_size,
                              hipStream_t stream) {
    const float* x     = (const float*)d_in[0];
    const float* w_fc0 = (const float*)d_in[1];
    const float* b_fc0 = (const float*)d_in[2];
    const float* w_fc1 = (const float*)d_in[3];
    const float* b_fc1 = (const float*)d_in[4];
    const float* ew1   = (const float*)d_in[5];
    const float* eb1   = (const float*)d_in[6];
    const float* ew2   = (const float*)d_in[7];
    const float* eb2   = (const float*)d_in[8];
    float* out = (float*)d_out;

    float* pmax = (float*)d_ws;                       // NQ*768
    float* psum = pmax + NQ * NB * DIM;               // NQ*768
    float* cof  = psum + NQ * NB * DIM;               // 48

    dim3 pg(NB * DIM, NQ);
    pool_partial<<<pg, 256, 0, stream>>>(x, pmax, psum);
    gate_kernel<<<1, 128, 0, stream>>>(pmax, psum, w_fc0, b_fc0, w_fc1, b_fc1, cof);
    dim3 grid(H / TY, DIM, NB);                       // (6, 96, 8)
    moe_kernel<<<grid, 256, 0, stream>>>(x, ew1, eb1, ew2, eb2, cof, out);
}

// Round 5
// 259.681 us; speedup vs baseline: 1.0055x; 1.0055x over previous
//
#include <hip/hip_runtime.h>
#include <math.h>

#define DIM 96
#define NE 6
#define NB 8
#define H 192
#define W 192
#define HW (H * W)
#define NQ 4            // pool partial quarters
#define QF4 (HW / 4 / NQ)  // 2304 float4 per quarter

typedef float f2 __attribute__((ext_vector_type(2)));

// ---------------- Kernel A: partial max+sum per (b,c,quarter) ----------------
__global__ __launch_bounds__(256) void pool_partial(const float* __restrict__ x,
                                                    float* __restrict__ pmax,
                                                    float* __restrict__ psum) {
    int bc = blockIdx.x;       // 0..767
    int q = blockIdx.y;        // 0..3
    const float4* xp = (const float4*)(x + (size_t)bc * HW) + q * QF4;
    int tid = threadIdx.x;
    float vmax = -INFINITY, vsum = 0.f;
    for (int i = tid; i < QF4; i += 256) {
        float4 v = xp[i];
        vmax = fmaxf(vmax, fmaxf(fmaxf(v.x, v.y), fmaxf(v.z, v.w)));
        vsum += v.x + v.y + v.z + v.w;
    }
    for (int off = 32; off; off >>= 1) {
        vmax = fmaxf(vmax, __shfl_down(vmax, off, 64));
        vsum += __shfl_down(vsum, off, 64);
    }
    __shared__ float smax[4], ssum[4];
    if ((tid & 63) == 0) { smax[tid >> 6] = vmax; ssum[tid >> 6] = vsum; }
    __syncthreads();
    if (tid == 0) {
        float m = smax[0], s = ssum[0];
        for (int w = 1; w < 4; ++w) { m = fmaxf(m, smax[w]); s += ssum[w]; }
        pmax[q * (NB * DIM) + bc] = m;
        psum[q * (NB * DIM) + bc] = s;
    }
}

// ---------------- Kernel B: gate (parallel dots from LDS) ----------------
__global__ __launch_bounds__(128) void gate_kernel(const float* __restrict__ pmax,
                                                   const float* __restrict__ psum,
                                                   const float* __restrict__ w_fc0,
                                                   const float* __restrict__ b_fc0,
                                                   const float* __restrict__ w_fc1,
                                                   const float* __restrict__ b_fc1,
                                                   float* __restrict__ cof) {
    __shared__ float sp[NB * DIM];       // pooled
    __shared__ float sw1[NE * DIM], sw0[NE * DIM];
    __shared__ float z1s[NB * NE], z0s[NB * NE];
    int tid = threadIdx.x;
    // merge pool partials -> pooled = max + mean
    for (int i = tid; i < NB * DIM; i += 128) {
        float m = pmax[i], s = psum[i];
        for (int q = 1; q < NQ; ++q) {
            m = fmaxf(m, pmax[q * (NB * DIM) + i]);
            s += psum[q * (NB * DIM) + i];
        }
        sp[i] = m + s * (1.0f / (float)HW);
    }
    for (int i = tid; i < NE * DIM; i += 128) {
        sw1[i] = w_fc1[i];
        sw0[i] = w_fc0[i];
    }
    __syncthreads();
    if (tid < 2 * NB * NE) {             // 96 threads: one dot each
        int pair = (tid < NB * NE) ? tid : tid - NB * NE;
        int b = pair / NE, e = pair - b * NE;
        const float* wp = ((tid < NB * NE) ? sw1 : sw0) + e * DIM;
        float z = (tid < NB * NE) ? b_fc1[e] : b_fc0[e];
        const float* pp = sp + b * DIM;
        for (int i = 0; i < DIM; ++i) z = fmaf(pp[i], wp[i], z);
        if (tid < NB * NE) z1s[pair] = z; else z0s[pair] = z;
    }
    __syncthreads();
    if (tid < NB) {
        int b = tid;
        float g[NE], noise[NE];
        for (int e = 0; e < NE; ++e) {
            float z1 = z1s[b * NE + e], z0 = z0s[b * NE + e];
            g[e] = (z1 > 0.f) ? z1 : 0.2f * z1;                 // leaky_relu 0.2
            noise[e] = (z0 > 20.f) ? z0 : log1pf(expf(z0));     // softplus
        }
        float mu = 0.f;
        for (int e = 0; e < NE; ++e) mu += noise[e];
        mu *= (1.0f / NE);
        float var = 0.f;
        for (int e = 0; e < NE; ++e) { float d = noise[e] - mu; var += d * d; }
        var *= (1.0f / (NE - 1));                               // ddof=1
        float sd = sqrtf(var);
        float scores[NE];
        for (int e = 0; e < NE; ++e) scores[e] = g[e] + (noise[e] - mu) / sd;
        bool chosen[NE] = {false, false, false, false, false, false};
        for (int k = 0; k < 3; ++k) {                           // top-3, ties -> lowest idx
            float best = -INFINITY; int bi = 0;
            for (int e = 0; e < NE; ++e)
                if (!chosen[e] && scores[e] > best) { best = scores[e]; bi = e; }
            chosen[bi] = true;
        }
        float m = -INFINITY;
        for (int e = 0; e < NE; ++e) if (chosen[e]) m = fmaxf(m, g[e]);
        float s = 0.f;
        for (int e = 0; e < NE; ++e) if (chosen[e]) s += expf(g[e] - m);
        float inv = 1.0f / s;
        for (int e = 0; e < NE; ++e)
            cof[b * NE + e] = chosen[e] ? expf(g[e] - m) * inv : 0.f;
    }
}

// ---------------- Kernel C: fused top-k expert dwconv-relu-dwconv (v5) ----------------
// v4 structure (no LDS, no barrier; per-lane 5-col window read from L2/L3-resident x)
// with deeper row bands: RPW 16 (warm-up redundancy 18/16 vs 10/8) and half the
// per-block prologue overhead. Conv math identical to v3/v4 -> bit-identical output.
#define TY 64
#define RPW 16                // rows per wave

__device__ __forceinline__ f2 splat2(float v) { f2 r; r.x = v; r.y = v; return r; }

// scalar 3x3 chain (association: w2*A2+bb innermost, rows A,B,C outward)
__device__ __forceinline__ float c3(const float* Wt, float bb,
                                    const float* A, const float* B,
                                    const float* Cc, int o) {
    float s = fmaf(Wt[2], A[o + 2], bb);
    s = fmaf(Wt[1], A[o + 1], s);
    s = fmaf(Wt[0], A[o], s);
    s = fmaf(Wt[5], B[o + 2], s);
    s = fmaf(Wt[4], B[o + 1], s);
    s = fmaf(Wt[3], B[o], s);
    s = fmaf(Wt[8], Cc[o + 2], s);
    s = fmaf(Wt[7], Cc[o + 1], s);
    s = fmaf(Wt[6], Cc[o], s);
    return s;
}

// packed pair-of-experts chain, x operands are splatted scalars (conv1)
__device__ __forceinline__ f2 c3p(const f2* Wt, f2 bb,
                                  const float* A, const float* B,
                                  const float* Cc, int o) {
    f2 s = __builtin_elementwise_fma(Wt[2], splat2(A[o + 2]), bb);
    s = __builtin_elementwise_fma(Wt[1], splat2(A[o + 1]), s);
    s = __builtin_elementwise_fma(Wt[0], splat2(A[o]), s);
    s = __builtin_elementwise_fma(Wt[5], splat2(B[o + 2]), s);
    s = __builtin_elementwise_fma(Wt[4], splat2(B[o + 1]), s);
    s = __builtin_elementwise_fma(Wt[3], splat2(B[o]), s);
    s = __builtin_elementwise_fma(Wt[8], splat2(Cc[o + 2]), s);
    s = __builtin_elementwise_fma(Wt[7], splat2(Cc[o + 1]), s);
    s = __builtin_elementwise_fma(Wt[6], splat2(Cc[o]), s);
    return s;
}

// packed chain with pair operands (conv2: ys halves are per-expert already)
__device__ __forceinline__ f2 c3q(const f2* Wt, f2 bb,
                                  const f2* A, const f2* B,
                                  const f2* Cc, int o) {
    f2 s = __builtin_elementwise_fma(Wt[2], A[o + 2], bb);
    s = __builtin_elementwise_fma(Wt[1], A[o + 1], s);
    s = __builtin_elementwise_fma(Wt[0], A[o], s);
    s = __builtin_elementwise_fma(Wt[5], B[o + 2], s);
    s = __builtin_elementwise_fma(Wt[4], B[o + 1], s);
    s = __builtin_elementwise_fma(Wt[3], B[o], s);
    s = __builtin_elementwise_fma(Wt[8], Cc[o + 2], s);
    s = __builtin_elementwise_fma(Wt[7], Cc[o + 1], s);
    s = __builtin_elementwise_fma(Wt[6], Cc[o], s);
    return s;
}

// load one x row's 5-col window (cols 3*lane-1 .. 3*lane+3) from global;
// OOB rows (wave-uniform) and OOB cols (lane 0 / lane 63) read as 0.
#define LOADROW(xr, dst) do {                                         \
    int _r = (xr);                                                    \
    if (_r >= 0 && _r < H) {                                          \
        const float* _q = xl + (size_t)_r * W;                        \
        float _v0 = _q[offm1];                                        \
        float _v1 = _q[0];                                            \
        float _v2 = _q[1];                                            \
        float _v3 = _q[2];                                            \
        float _v4 = _q[off3];                                         \
        if (l0)  _v0 = 0.f;                                           \
        if (l63) _v4 = 0.f;                                           \
        (dst)[0] = _v0; (dst)[1] = _v1; (dst)[2] = _v2;               \
        (dst)[3] = _v3; (dst)[4] = _v4;                               \
    } else {                                                          \
        (dst)[0] = 0.f; (dst)[1] = 0.f; (dst)[2] = 0.f;               \
        (dst)[3] = 0.f; (dst)[4] = 0.f;                               \
    }                                                                 \
} while (0)

__global__ __launch_bounds__(256, 3) void moe_kernel(const float* __restrict__ x,
                                                     const float* __restrict__ ew1,
                                                     const float* __restrict__ eb1,
                                                     const float* __restrict__ ew2,
                                                     const float* __restrict__ eb2,
                                                     const float* __restrict__ cof,
                                                     float* __restrict__ out) {
    const int sb = blockIdx.x;           // stripe 0..2
    const int c = blockIdx.y;
    const int b = blockIdx.z;
    const int ty0 = sb * TY;
    const int tid = threadIdx.x;
    const int lane = tid & 63;
    const int wv = tid >> 6;
    const bool l0 = (lane == 0);
    const bool l63 = (lane == 63);

    // ---- compact the (always exactly 3) chosen experts; hoist to SGPR ----
    const float* cofb = cof + b * NE;
    int e0 = 0, e1 = 0, e2 = 0;
    float q0 = 0.f, q1 = 0.f, q2 = 0.f;
    int n = 0;
    #pragma unroll
    for (int e = 0; e < NE; ++e) {
        float ce = cofb[e];
        if (ce != 0.f) {
            if (n == 0)      { e0 = e; q0 = ce; }
            else if (n == 1) { e1 = e; q1 = ce; }
            else if (n == 2) { e2 = e; q2 = ce; }
            ++n;
        }
    }
    e0 = __builtin_amdgcn_readfirstlane(e0);
    e1 = __builtin_amdgcn_readfirstlane(e1);
    e2 = __builtin_amdgcn_readfirstlane(e2);
    q0 = __int_as_float(__builtin_amdgcn_readfirstlane(__float_as_int(q0)));
    q1 = __int_as_float(__builtin_amdgcn_readfirstlane(__float_as_int(q1)));
    q2 = __int_as_float(__builtin_amdgcn_readfirstlane(__float_as_int(q2)));

    // weights: pair (e0,e1) packed, e2 scalar
    f2 W1p[9], W2p[9];
    float W1s[9], W2s[9];
    {
        const float* p10 = ew1 + (size_t)(e0 * DIM + c) * 9;
        const float* p11 = ew1 + (size_t)(e1 * DIM + c) * 9;
        const float* p12 = ew1 + (size_t)(e2 * DIM + c) * 9;
        const float* p20 = ew2 + (size_t)(e0 * DIM + c) * 9;
        const float* p21 = ew2 + (size_t)(e1 * DIM + c) * 9;
        const float* p22 = ew2 + (size_t)(e2 * DIM + c) * 9;
        #pragma unroll
        for (int k = 0; k < 9; ++k) {
            W1p[k].x = p10[k]; W1p[k].y = p11[k]; W1s[k] = p12[k];
            W2p[k].x = p20[k]; W2p[k].y = p21[k]; W2s[k] = p22[k];
        }
    }
    f2 B1p, B2p;
    B1p.x = eb1[e0 * DIM + c]; B1p.y = eb1[e1 * DIM + c];
    B2p.x = eb2[e0 * DIM + c]; B2p.y = eb2[e1 * DIM + c];
    const float B1s = eb1[e2 * DIM + c];
    const float B2s = eb2[e2 * DIM + c];
    const float CE0 = q0, CE1 = q1, CE2 = q2;

    const int r0 = ty0 + wv * RPW;       // first conv2 output row of this wave
    const float* xl = x + ((size_t)(b * DIM + c)) * HW + 3 * lane;  // col 3*lane
    const int offm1 = l0 ? 0 : -1;       // clamped col offsets (value zeroed after load)
    const int off3  = l63 ? 2 : 3;

    float X[4][5];                       // rotating x window: 4 rows x 5 cols
    f2 Yp[3][5];                         // pair-expert ys window: 3 rows x 5 cols
    float Ysc[3][5];                     // scalar-expert ys window
    LOADROW(r0 - 2, X[0]);
    LOADROW(r0 - 1, X[1]);
    LOADROW(r0,     X[2]);

    float* op = out + ((size_t)(b * DIM + c)) * HW + (size_t)r0 * W + 3 * lane;
    const f2 zero2 = splat2(0.f);

    #pragma unroll
    for (int j = 0; j < RPW + 2; ++j) {  // ys row ry = r0-1+j; out row r0+j-2 for j>=2
        if (j <= RPW)                    // prefetch row r0+j+1 (used as xC next iter)
            LOADROW(r0 + j + 1, X[(j + 3) & 3]);
        const float* xA = X[j & 3];          // row ry-1
        const float* xB = X[(j + 1) & 3];    // row ry
        const float* xC = X[(j + 2) & 3];    // row ry+1

        // conv1 + bias + relu
        f2 y0p = c3p(W1p, B1p, xA, xB, xC, 0);
        f2 y1p = c3p(W1p, B1p, xA, xB, xC, 1);
        f2 y2p = c3p(W1p, B1p, xA, xB, xC, 2);
        float y0s = c3(W1s, B1s, xA, xB, xC, 0);
        float y1s = c3(W1s, B1s, xA, xB, xC, 1);
        float y2s = c3(W1s, B1s, xA, xB, xC, 2);
        y0p = __builtin_elementwise_max(y0p, zero2);
        y1p = __builtin_elementwise_max(y1p, zero2);
        y2p = __builtin_elementwise_max(y2p, zero2);
        y0s = fmaxf(y0s, 0.f); y1s = fmaxf(y1s, 0.f); y2s = fmaxf(y2s, 0.f);
        if (j == 0 || j == RPW + 1) {        // only edge rows can be out of image
            int ry = r0 - 1 + j;
            if (ry < 0 || ry >= H) {
                y0p = zero2; y1p = zero2; y2p = zero2;
                y0s = 0.f; y1s = 0.f; y2s = 0.f;  // conv2 zero-pad
            }
        }
        // halo columns via shuffles (per expert half)
        float ylpx = __shfl_up(y2p.x, 1), ylpy = __shfl_up(y2p.y, 1);
        float yls = __shfl_up(y2s, 1);
        float yrpx = __shfl_down(y0p.x, 1), yrpy = __shfl_down(y0p.y, 1);
        float yrs = __shfl_down(y0s, 1);
        if (l0)  { ylpx = 0.f; ylpy = 0.f; yls = 0.f; }   // ys col -1 == 0
        if (l63) { yrpx = 0.f; yrpy = 0.f; yrs = 0.f; }   // ys col 192 == 0
        f2* ywp = Yp[j % 3];
        float* yws = Ysc[j % 3];
        ywp[0].x = ylpx; ywp[0].y = ylpy;
        ywp[1] = y0p; ywp[2] = y1p; ywp[3] = y2p;
        ywp[4].x = yrpx; ywp[4].y = yrpy;
        yws[0] = yls; yws[1] = y0s; yws[2] = y1s; yws[3] = y2s; yws[4] = yrs;

        if (j >= 2) {
            const f2* pA = Yp[(j + 1) % 3];      // ys row ro-1
            const f2* pB = Yp[(j + 2) % 3];      // ys row ro
            const f2* pC = ywp;                  // ys row ro+1
            const float* sA = Ysc[(j + 1) % 3];
            const float* sB = Ysc[(j + 2) % 3];
            const float* sC = yws;
            f2 s0p = c3q(W2p, B2p, pA, pB, pC, 0);
            f2 s1p = c3q(W2p, B2p, pA, pB, pC, 1);
            f2 s2p = c3q(W2p, B2p, pA, pB, pC, 2);
            float s0s = c3(W2s, B2s, sA, sB, sC, 0);
            float s1s = c3(W2s, B2s, sA, sB, sC, 1);
            float s2s = c3(W2s, B2s, sA, sB, sC, 2);
            // accumulate in the SAME order as v2: e0, e1, e2 fma chain
            float a0 = fmaf(CE2, s0s, fmaf(CE1, s0p.y, fmaf(CE0, s0p.x, 0.f)));
            float a1 = fmaf(CE2, s1s, fmaf(CE1, s1p.y, fmaf(CE0, s1p.x, 0.f)));
            float a2 = fmaf(CE2, s2s, fmaf(CE1, s2p.y, fmaf(CE0, s2p.x, 0.f)));
            op[0] = a0; op[1] = a1; op[2] = a2;
            op += W;
        }
    }
}

extern "C" void kernel_launch(void* const* d_in, const int* in_sizes, int n_in,
                              void* d_out, int out_size, void* d_ws, size_t ws_size,
                              hipStream_t stream) {
    const float* x     = (const float*)d_in[0];
    const float* w_fc0 = (const float*)d_in[1];
    const float* b_fc0 = (const float*)d_in[2];
    const float* w_fc1 = (const float*)d_in[3];
    const float* b_fc1 = (const float*)d_in[4];
    const float* ew1   = (const float*)d_in[5];
    const float* eb1   = (const float*)d_in[6];
    const float* ew2   = (const float*)d_in[7];
    const float* eb2   = (const float*)d_in[8];
    float* out = (float*)d_out;

    float* pmax = (float*)d_ws;                       // NQ*768
    float* psum = pmax + NQ * NB * DIM;               // NQ*768
    float* cof  = psum + NQ * NB * DIM;               // 48

    dim3 pg(NB * DIM, NQ);
    pool_partial<<<pg, 256, 0, stream>>>(x, pmax, psum);
    gate_kernel<<<1, 128, 0, stream>>>(pmax, psum, w_fc0, b_fc0, w_fc1, b_fc1, cof);
    dim3 grid(H / TY, DIM, NB);                       // (3, 96, 8)
    moe_kernel<<<grid, 256, 0, stream>>>(x, ew1, eb1, ew2, eb2, cof, out);
}